// Round 6
// baseline (673.561 us; speedup 1.0000x reference)
//
#include <hip/hip_runtime.h>
#include <hip/hip_bf16.h>
#include <stdint.h>

// Problem dims (fixed by the reference)
#define DM 768
#define DI 1536
#define DSTATE 16
#define RNK 48
#define BB 2
#define LL 1024
#define ML (BB * LL)  // 2048 rows (b*l flattened)

typedef unsigned short u16;
typedef __bf16 bf16x8 __attribute__((ext_vector_type(8)));
typedef float f32x4 __attribute__((ext_vector_type(4)));

struct __align__(8) u16x4_t { u16 x, y, z, w; };

__device__ __forceinline__ float b2f(u16 u) {
  union { uint32_t i; float f; } v; v.i = ((uint32_t)u) << 16; return v.f;
}
__device__ __forceinline__ u16 f2b(float f) {
  union { float f; uint32_t i; } v; v.f = f;
  uint32_t r = v.i + 0x7FFFu + ((v.i >> 16) & 1u);  // RNE
  return (u16)(r >> 16);
}
__device__ __forceinline__ float silu_f(float x) { return x / (1.f + __expf(-x)); }
__device__ __forceinline__ u16x4_t cvt4(float4 v) {
  u16x4_t o; o.x = f2b(v.x); o.y = f2b(v.y); o.z = f2b(v.z); o.w = f2b(v.w); return o;
}

// ---------------------------------------------------------------------------
// Fused fp32->bf16 conversion of all GEMM operands + proj-weight concat.
// Segments (in float4 units): x | Wis | Wig | Wout | concat(2 dirs)
// concat rows: [0..47]=W_dt, [48..63]=W_B, [64..79]=W_C, [80..127]=0
// ---------------------------------------------------------------------------
#define SEG_X    (ML * DM / 4)        // 393216
#define SEG_W    (DI * DM / 4)        // 294912 (Wis, Wig, Wout all same count)
#define SEG_CAT  (128 * DI / 4)       // 49152 per direction
__global__ __launch_bounds__(256) void convert_kernel(
    const float4* __restrict__ x, const float4* __restrict__ wis,
    const float4* __restrict__ wig, const float4* __restrict__ wout,
    const float* __restrict__ W_dt, const float* __restrict__ W_B,
    const float* __restrict__ W_C, const float* __restrict__ W_dt_b,
    const float* __restrict__ W_B_b, const float* __restrict__ W_C_b,
    u16x4_t* __restrict__ xb, u16x4_t* __restrict__ wisb,
    u16x4_t* __restrict__ wigb, u16x4_t* __restrict__ woutb,
    u16x4_t* __restrict__ wcf, u16x4_t* __restrict__ wcb)
{
  int idx = blockIdx.x * 256 + threadIdx.x;
  if (idx < SEG_X) { xb[idx] = cvt4(x[idx]); return; }
  idx -= SEG_X;
  if (idx < SEG_W) { wisb[idx] = cvt4(wis[idx]); return; }
  idx -= SEG_W;
  if (idx < SEG_W) { wigb[idx] = cvt4(wig[idx]); return; }
  idx -= SEG_W;
  if (idx < SEG_W) { woutb[idx] = cvt4(wout[idx]); return; }
  idx -= SEG_W;
  // concat segment: idx in [0, 2*SEG_CAT)
  int dir = idx / SEG_CAT;
  int rem = idx % SEG_CAT;
  int row = rem / (DI / 4), k4 = rem % (DI / 4);
  const float* src = nullptr;
  if (row < 48)      src = (dir ? W_dt_b : W_dt) + (size_t)row * DI + k4 * 4;
  else if (row < 64) src = (dir ? W_B_b  : W_B)  + (size_t)(row - 48) * DI + k4 * 4;
  else if (row < 80) src = (dir ? W_C_b  : W_C)  + (size_t)(row - 64) * DI + k4 * 4;
  u16x4_t o;
  if (src) o = cvt4(*(const float4*)src);
  else { o.x = 0; o.y = 0; o.z = 0; o.w = 0; }
  (dir ? wcb : wcf)[rem] = o;
}

// ---------------------------------------------------------------------------
// Generic bf16 GEMM: C[m,n] = sum_k A[m,k] * B[n,k]   (A: MxK, B: NxK row-major)
// 128x128 tile, 4 waves (2x2 of 64x64), 16x16x32 MFMA, uint4 VGPR staging.
// Requires M%128==0, N%128==0, K%32==0.
// epi: 0 = store bf16, 2 = store fp32.  Dual-B mode (B1!=null): blocks with
// bn>=Nsplit read B1 (col bn-Nsplit) and apply SiLU before bf16 store.
// blockIdx.z==1 switches to (A2,B2,C2) — batches fwd/bwd proj GEMMs.
// NOTE: validated vs fp32 pipeline (rounds 3/4 bit-identical after bf16 round).
// ---------------------------------------------------------------------------
__global__ __launch_bounds__(256) void gemm_bt(
    const u16* __restrict__ A, const u16* __restrict__ B0,
    const u16* __restrict__ B1, int Nsplit,
    void* __restrict__ Cout, int M, int N, int K, int ldc, int epi,
    const u16* __restrict__ A2, const u16* __restrict__ B2,
    void* __restrict__ C2)
{
  if (blockIdx.z) { A = A2; B0 = B2; Cout = C2; }
  __shared__ alignas(16) u16 As[128 * 32];
  __shared__ alignas(16) u16 Bs[128 * 32];
  const int tid = threadIdx.x;
  const int wave = tid >> 6, lane = tid & 63;
  const int bm = blockIdx.y * 128;
  const int bn = blockIdx.x * 128;

  const u16* Bmat = B0;
  int ncol0 = bn;
  int epi_l = epi;
  if (B1 != nullptr && bn >= Nsplit) { Bmat = B1; ncol0 = bn - Nsplit; epi_l = 1; }

  // staging: 512 chunks of 16B per operand; thread t handles chunks t and t+256.
  const int c0 = tid, c1 = tid + 256;
  const u16* gA0 = A + (size_t)(bm + (c0 >> 2)) * K + (c0 & 3) * 8;
  const u16* gA1 = A + (size_t)(bm + (c1 >> 2)) * K + (c1 & 3) * 8;
  const u16* gB0 = Bmat + (size_t)(ncol0 + (c0 >> 2)) * K + (c0 & 3) * 8;
  const u16* gB1 = Bmat + (size_t)(ncol0 + (c1 >> 2)) * K + (c1 & 3) * 8;
  uint4* lA0 = (uint4*)&As[c0 * 8]; uint4* lA1 = (uint4*)&As[c1 * 8];
  uint4* lB0 = (uint4*)&Bs[c0 * 8]; uint4* lB1 = (uint4*)&Bs[c1 * 8];

  const int wm = (wave & 1) * 64, wn = (wave >> 1) * 64;
  const int rl = lane & 15, q = lane >> 4;

  f32x4 acc[4][4];
#pragma unroll
  for (int i = 0; i < 4; ++i)
#pragma unroll
    for (int j = 0; j < 4; ++j) acc[i][j] = (f32x4){0.f, 0.f, 0.f, 0.f};

  const bf16x8* AsV = (const bf16x8*)As;
  const bf16x8* BsV = (const bf16x8*)Bs;

  for (int k0 = 0; k0 < K; k0 += 32) {
    uint4 ra0 = *(const uint4*)(gA0 + k0);
    uint4 ra1 = *(const uint4*)(gA1 + k0);
    uint4 rb0 = *(const uint4*)(gB0 + k0);
    uint4 rb1 = *(const uint4*)(gB1 + k0);
    *lA0 = ra0; *lA1 = ra1; *lB0 = rb0; *lB1 = rb1;
    __syncthreads();
    bf16x8 af[4], bfv[4];
#pragma unroll
    for (int s = 0; s < 4; ++s) {
      af[s]  = AsV[(wm + s * 16 + rl) * 4 + q];
      bfv[s] = BsV[(wn + s * 16 + rl) * 4 + q];
    }
#pragma unroll
    for (int i = 0; i < 4; ++i)
#pragma unroll
      for (int j = 0; j < 4; ++j)
        acc[i][j] = __builtin_amdgcn_mfma_f32_16x16x32_bf16(af[i], bfv[j], acc[i][j], 0, 0, 0);
    __syncthreads();
  }

  // epilogue: C/D layout col=lane&15, row=(lane>>4)*4+reg  [verified m89/m91]
#pragma unroll
  for (int i = 0; i < 4; ++i) {
#pragma unroll
    for (int j = 0; j < 4; ++j) {
#pragma unroll
      for (int r = 0; r < 4; ++r) {
        int row = bm + wm + i * 16 + q * 4 + r;
        int col = bn + wn + j * 16 + rl;
        float v = acc[i][j][r];
        if (epi_l == 1) v = silu_f(v);
        if (epi == 2) ((float*)Cout)[(size_t)row * ldc + col] = v;
        else          ((u16*)Cout)[(size_t)row * ldc + col] = f2b(v);
      }
    }
  }
}

// ---------------------------------------------------------------------------
// Causal depthwise conv (K=4, fp32 weights) + SiLU, fwd on xs and bwd on
// reversed xs. xs lives in cols [0,1536) of xsg (ld=3072, bf16).
// xcb is produced in REVERSED space.
// ---------------------------------------------------------------------------
__global__ void conv_kernel(
    const u16* __restrict__ xsg,
    const float* __restrict__ cw, const float* __restrict__ cb,
    const float* __restrict__ cwb, const float* __restrict__ cbb,
    u16* __restrict__ xc, u16* __restrict__ xcb)
{
  int idx = blockIdx.x * 256 + threadIdx.x;      // over ML*DI
  int d = idx % DI;
  int row = idx / DI;
  int l = row % LL, b = row / LL;
  const u16* base = xsg + (size_t)b * LL * 3072 + d;

  float4 wf = *(const float4*)(cw + d * 4);
  float4 wb = *(const float4*)(cwb + d * 4);
  float wfk[4] = {wf.x, wf.y, wf.z, wf.w};
  float wbk[4] = {wb.x, wb.y, wb.z, wb.w};

  float accf = cb[d];
  float accb = cbb[d];
#pragma unroll
  for (int k = 0; k < 4; ++k) {
    int ls = l - 3 + k;
    if (ls >= 0) {
      accf += wfk[k] * b2f(base[(size_t)ls * 3072]);            // forward seq
      accb += wbk[k] * b2f(base[(size_t)(LL - 1 - ls) * 3072]); // reversed seq
    }
  }
  xc[idx]  = f2b(silu_f(accf));
  xcb[idx] = f2b(silu_f(accb));
}

// ---------------------------------------------------------------------------
// delta = softplus(dt_low @ dtW^T + dtb), fp32 out.  proj row layout:
// [0..47]=dt_low, [48..63]=Bm, [64..79]=Cm (fp32, ld=128). dtW/dtb fp32.
// ---------------------------------------------------------------------------
__global__ __launch_bounds__(256) void delta_kernel(
    const float* __restrict__ proj_f, const float* __restrict__ proj_b,
    const float* __restrict__ dtW, const float* __restrict__ dtW_b,
    const float* __restrict__ dtb, const float* __restrict__ dtb_b,
    float* __restrict__ delta_f, float* __restrict__ delta_b)
{
  const int dir = blockIdx.z;
  const float* proj = dir ? proj_b : proj_f;
  const float* W = dir ? dtW_b : dtW;
  const float* bias = dir ? dtb_b : dtb;
  float* outp = dir ? delta_b : delta_f;
  const int row = blockIdx.x;                        // 0..2047
  const int d = blockIdx.y * 256 + threadIdx.x;      // 0..1535

  __shared__ float dl[RNK];
  if (threadIdx.x < RNK) dl[threadIdx.x] = proj[(size_t)row * 128 + threadIdx.x];
  __syncthreads();

  float s = bias[d];
  const float4* w4 = (const float4*)(W + (size_t)d * RNK);
#pragma unroll
  for (int j = 0; j < RNK / 4; ++j) {
    float4 w = w4[j];
    s += dl[j * 4 + 0] * w.x + dl[j * 4 + 1] * w.y +
         dl[j * 4 + 2] * w.z + dl[j * 4 + 3] * w.w;
  }
  float sp = (s > 20.f) ? s : log1pf(__expf(s));
  outp[(size_t)row * DI + d] = sp;
}

// ---------------------------------------------------------------------------
// Selective scan. 16 lanes per channel (one state per lane), h in registers,
// shuffle-xor reduction over states for y. Sequential over L.
// A_log/Dp are fp32.
// ---------------------------------------------------------------------------
__global__ __launch_bounds__(256) void scan_kernel(
    const float* __restrict__ delta_f, const float* __restrict__ delta_b,
    const u16* __restrict__ xc_f, const u16* __restrict__ xc_b,
    const float* __restrict__ proj_f, const float* __restrict__ proj_b,
    const float* __restrict__ A_log, const float* __restrict__ A_log_b,
    const float* __restrict__ Dp, const float* __restrict__ Dp_b,
    u16* __restrict__ y_f, u16* __restrict__ y_b)
{
  const int dir = blockIdx.z;
  const float* delta = dir ? delta_b : delta_f;
  const u16* xc = dir ? xc_b : xc_f;
  const float* proj = dir ? proj_b : proj_f;
  const float* Al = dir ? A_log_b : A_log;
  const float* Dpp = dir ? Dp_b : Dp;
  u16* y = dir ? y_b : y_f;

  const int b = blockIdx.y;
  const int c = threadIdx.x >> 4, n = threadIdx.x & 15;
  const int d = blockIdx.x * 16 + c;

  const float* dbase = delta + (size_t)b * LL * DI + d;
  const u16* xbase = xc + (size_t)b * LL * DI + d;
  const float* pB = proj + (size_t)b * LL * 128 + 48 + n;
  const float* pC = pB + 16;
  u16* ybase = y + (size_t)b * LL * DI + d;

  const float Av = -__expf(Al[d * DSTATE + n]);
  const float Dv = Dpp[d];
  float h = 0.f;

  // software-pipelined loads (next-l prefetch)
  float dl = dbase[0];
  float xv = b2f(xbase[0]);
  float Bv = pB[0];
  float Cv = pC[0];
  for (int l = 0; l < LL; ++l) {
    float dl_n = 0.f, xv_n = 0.f, Bv_n = 0.f, Cv_n = 0.f;
    if (l + 1 < LL) {
      dl_n = dbase[(size_t)(l + 1) * DI];
      xv_n = b2f(xbase[(size_t)(l + 1) * DI]);
      Bv_n = pB[(size_t)(l + 1) * 128];
      Cv_n = pC[(size_t)(l + 1) * 128];
    }
    h = __expf(dl * Av) * h + (dl * xv) * Bv;
    float p = h * Cv;
    p += __shfl_xor(p, 1);
    p += __shfl_xor(p, 2);
    p += __shfl_xor(p, 4);
    p += __shfl_xor(p, 8);
    if (n == 0) ybase[(size_t)l * DI] = f2b(p + Dv * xv);
    dl = dl_n; xv = xv_n; Bv = Bv_n; Cv = Cv_n;
  }
}

// ---------------------------------------------------------------------------
// y_comb[l] = 0.5 * silu(z[l]) * (y_f[l] + y_b_rev[L-1-l]); g=silu(z) is
// already in cols [1536,3072) of xsg. Writes IN PLACE over yf (index-preserving
// on the aliased buffer -> race-free).
// ---------------------------------------------------------------------------
__global__ void combine_kernel(
    const u16* __restrict__ ybr, const u16* __restrict__ xsg, u16* yf)
{
  int idx = blockIdx.x * 256 + threadIdx.x;      // over ML*DI
  int d = idx % DI;
  int row = idx / DI;
  int l = row % LL, b = row / LL;
  float g = b2f(xsg[(size_t)row * 3072 + DI + d]);
  float vb = b2f(ybr[((size_t)b * LL + (LL - 1 - l)) * DI + d]);
  float v = 0.5f * (b2f(yf[idx]) + vb) * g;
  yf[idx] = f2b(v);
}

// ---------------------------------------------------------------------------
extern "C" void kernel_launch(void* const* d_in, const int* in_sizes, int n_in,
                              void* d_out, int out_size, void* d_ws, size_t ws_size,
                              hipStream_t stream)
{
  // All inputs fp32 (reference setup_inputs). OUTPUT IS FP32 (reference
  // returns float32; round-5 beacon experiment proved harness reads fp32).
  const float* x       = (const float*)d_in[0];
  const float* Wis     = (const float*)d_in[1];
  const float* Wig     = (const float*)d_in[2];
  const float* conv_w  = (const float*)d_in[3];
  const float* conv_b  = (const float*)d_in[4];
  const float* conv_wb = (const float*)d_in[5];
  const float* conv_bb = (const float*)d_in[6];
  const float* W_dt    = (const float*)d_in[7];
  const float* W_B     = (const float*)d_in[8];
  const float* W_C     = (const float*)d_in[9];
  const float* dtW     = (const float*)d_in[10];
  const float* dtb     = (const float*)d_in[11];
  const float* A_log   = (const float*)d_in[12];
  const float* Dp      = (const float*)d_in[13];
  const float* W_dt_b  = (const float*)d_in[14];
  const float* W_B_b   = (const float*)d_in[15];
  const float* W_C_b   = (const float*)d_in[16];
  const float* dtW_b   = (const float*)d_in[17];
  const float* dtb_b   = (const float*)d_in[18];
  const float* A_log_b = (const float*)d_in[19];
  const float* Dp_b    = (const float*)d_in[20];
  const float* W_out   = (const float*)d_in[21];

  char* ws = (char*)d_ws;
  size_t off = 0;
  auto alloc = [&](size_t bytes) -> char* {
    char* p = ws + off; off += (bytes + 255) & ~(size_t)255; return p;
  };
  u16*   xb    = (u16*)alloc((size_t)ML * DM * 2);     // bf16 x
  u16*   wisb  = (u16*)alloc((size_t)DI * DM * 2);
  u16*   wigb  = (u16*)alloc((size_t)DI * DM * 2);
  u16*   woutb = (u16*)alloc((size_t)DM * DI * 2);
  u16*   xsg = (u16*)alloc((size_t)ML * 3072 * 2);     // [xs | silu(z)]
  u16*   xc  = (u16*)alloc((size_t)ML * DI * 2);
  u16*   xcb = (u16*)alloc((size_t)ML * DI * 2);       // reversed space
  u16*   wcf = (u16*)alloc((size_t)128 * DI * 2);
  u16*   wcb = (u16*)alloc((size_t)128 * DI * 2);
  float* pf  = (float*)alloc((size_t)ML * 128 * 4);
  float* pb  = (float*)alloc((size_t)ML * 128 * 4);
  float* df  = (float*)alloc((size_t)ML * DI * 4);
  float* db  = (float*)alloc((size_t)ML * DI * 4);
  u16*   yf  = (u16*)alloc((size_t)ML * DI * 2);       // later holds combined y
  u16*   ybr = (u16*)alloc((size_t)ML * DI * 2);       // reversed space
  // total ~77 MB

  // 1. fp32->bf16 conversion + proj-weight concat (one fused launch)
  const int conv_total = SEG_X + 3 * SEG_W + 2 * SEG_CAT;   // float4 units
  convert_kernel<<<(conv_total + 255) / 256, 256, 0, stream>>>(
      (const float4*)x, (const float4*)Wis, (const float4*)Wig, (const float4*)W_out,
      W_dt, W_B, W_C, W_dt_b, W_B_b, W_C_b,
      (u16x4_t*)xb, (u16x4_t*)wisb, (u16x4_t*)wigb, (u16x4_t*)woutb,
      (u16x4_t*)wcf, (u16x4_t*)wcb);

  // 2. in-proj: [xs | silu(z)] = x @ [Wis; Wig]^T   (M=2048, N=3072, K=768)
  gemm_bt<<<dim3(3072 / 128, ML / 128, 1), 256, 0, stream>>>(
      xb, wisb, wigb, DI, xsg, ML, 3072, DM, 3072, 0, nullptr, nullptr, nullptr);

  // 3. causal conv + silu (fwd + reversed)
  conv_kernel<<<(ML * DI) / 256, 256, 0, stream>>>(
      xsg, conv_w, conv_b, conv_wb, conv_bb, xc, xcb);

  // 4. proj GEMMs: [dt_low|Bm|Cm|pad] = xc @ wcat^T  (N=128 padded, fp32 out),
  //    both directions in one launch via blockIdx.z
  gemm_bt<<<dim3(1, ML / 128, 2), 256, 0, stream>>>(
      xc, wcf, nullptr, 1 << 30, pf, ML, 128, DI, 128, 2, xcb, wcb, pb);

  // 5. delta (fp32, both dirs)
  delta_kernel<<<dim3(ML, DI / 256, 2), 256, 0, stream>>>(
      pf, pb, dtW, dtW_b, dtb, dtb_b, df, db);

  // 6. selective scan (both dirs)
  scan_kernel<<<dim3(DI / 16, BB, 2), 256, 0, stream>>>(
      df, db, xc, xcb, pf, pb, A_log, A_log_b, Dp, Dp_b, yf, ybr);

  // 7. gated combine + un-reverse (in place over yf)
  combine_kernel<<<(ML * DI) / 256, 256, 0, stream>>>(ybr, xsg, yf);

  // 8. out-proj: out = yf @ W_out^T  (M=2048, N=768, K=1536), FP32 to d_out
  gemm_bt<<<dim3(DM / 128, ML / 128, 1), 256, 0, stream>>>(
      yf, woutb, nullptr, 1 << 30, d_out, ML, DM, DI, DM, 2, nullptr, nullptr, nullptr);
}

// Round 7
// 377.771 us; speedup vs baseline: 1.7830x; 1.7830x over previous
//
#include <hip/hip_runtime.h>
#include <hip/hip_bf16.h>
#include <stdint.h>

// Problem dims (fixed by the reference)
#define DM 768
#define DI 1536
#define DSTATE 16
#define RNK 48
#define BB 2
#define LL 1024
#define ML (BB * LL)  // 2048 rows (b*l flattened)

// segmented scan config
#define NSEG 32
#define SEGL (LL / NSEG)   // 32

typedef unsigned short u16;
typedef __bf16 bf16x8 __attribute__((ext_vector_type(8)));
typedef float f32x4 __attribute__((ext_vector_type(4)));

struct __align__(8) u16x4_t { u16 x, y, z, w; };

__device__ __forceinline__ float b2f(u16 u) {
  union { uint32_t i; float f; } v; v.i = ((uint32_t)u) << 16; return v.f;
}
__device__ __forceinline__ u16 f2b(float f) {
  union { float f; uint32_t i; } v; v.f = f;
  uint32_t r = v.i + 0x7FFFu + ((v.i >> 16) & 1u);  // RNE
  return (u16)(r >> 16);
}
__device__ __forceinline__ float silu_f(float x) { return x / (1.f + __expf(-x)); }
__device__ __forceinline__ u16x4_t cvt4(float4 v) {
  u16x4_t o; o.x = f2b(v.x); o.y = f2b(v.y); o.z = f2b(v.z); o.w = f2b(v.w); return o;
}

// ---------------------------------------------------------------------------
// Fused fp32->bf16 conversion of all GEMM operands + proj-weight concat.
// ---------------------------------------------------------------------------
#define SEG_X    (ML * DM / 4)
#define SEG_W    (DI * DM / 4)
#define SEG_CAT  (128 * DI / 4)
__global__ __launch_bounds__(256) void convert_kernel(
    const float4* __restrict__ x, const float4* __restrict__ wis,
    const float4* __restrict__ wig, const float4* __restrict__ wout,
    const float* __restrict__ W_dt, const float* __restrict__ W_B,
    const float* __restrict__ W_C, const float* __restrict__ W_dt_b,
    const float* __restrict__ W_B_b, const float* __restrict__ W_C_b,
    u16x4_t* __restrict__ xb, u16x4_t* __restrict__ wisb,
    u16x4_t* __restrict__ wigb, u16x4_t* __restrict__ woutb,
    u16x4_t* __restrict__ wcf, u16x4_t* __restrict__ wcb)
{
  int idx = blockIdx.x * 256 + threadIdx.x;
  if (idx < SEG_X) { xb[idx] = cvt4(x[idx]); return; }
  idx -= SEG_X;
  if (idx < SEG_W) { wisb[idx] = cvt4(wis[idx]); return; }
  idx -= SEG_W;
  if (idx < SEG_W) { wigb[idx] = cvt4(wig[idx]); return; }
  idx -= SEG_W;
  if (idx < SEG_W) { woutb[idx] = cvt4(wout[idx]); return; }
  idx -= SEG_W;
  int dir = idx / SEG_CAT;
  int rem = idx % SEG_CAT;
  int row = rem / (DI / 4), k4 = rem % (DI / 4);
  const float* src = nullptr;
  if (row < 48)      src = (dir ? W_dt_b : W_dt) + (size_t)row * DI + k4 * 4;
  else if (row < 64) src = (dir ? W_B_b  : W_B)  + (size_t)(row - 48) * DI + k4 * 4;
  else if (row < 80) src = (dir ? W_C_b  : W_C)  + (size_t)(row - 64) * DI + k4 * 4;
  u16x4_t o;
  if (src) o = cvt4(*(const float4*)src);
  else { o.x = 0; o.y = 0; o.z = 0; o.w = 0; }
  (dir ? wcb : wcf)[rem] = o;
}

// ---------------------------------------------------------------------------
// Generic bf16 GEMM (validated rounds 3/4/6): C = A (MxK) @ B^T (NxK).
// 128x128 tile, 4 waves, 16x16x32 MFMA, uint4 staging.
// ---------------------------------------------------------------------------
__global__ __launch_bounds__(256) void gemm_bt(
    const u16* __restrict__ A, const u16* __restrict__ B0,
    const u16* __restrict__ B1, int Nsplit,
    void* __restrict__ Cout, int M, int N, int K, int ldc, int epi,
    const u16* __restrict__ A2, const u16* __restrict__ B2,
    void* __restrict__ C2)
{
  if (blockIdx.z) { A = A2; B0 = B2; Cout = C2; }
  __shared__ alignas(16) u16 As[128 * 32];
  __shared__ alignas(16) u16 Bs[128 * 32];
  const int tid = threadIdx.x;
  const int wave = tid >> 6, lane = tid & 63;
  const int bm = blockIdx.y * 128;
  const int bn = blockIdx.x * 128;

  const u16* Bmat = B0;
  int ncol0 = bn;
  int epi_l = epi;
  if (B1 != nullptr && bn >= Nsplit) { Bmat = B1; ncol0 = bn - Nsplit; epi_l = 1; }

  const int c0 = tid, c1 = tid + 256;
  const u16* gA0 = A + (size_t)(bm + (c0 >> 2)) * K + (c0 & 3) * 8;
  const u16* gA1 = A + (size_t)(bm + (c1 >> 2)) * K + (c1 & 3) * 8;
  const u16* gB0 = Bmat + (size_t)(ncol0 + (c0 >> 2)) * K + (c0 & 3) * 8;
  const u16* gB1 = Bmat + (size_t)(ncol0 + (c1 >> 2)) * K + (c1 & 3) * 8;
  uint4* lA0 = (uint4*)&As[c0 * 8]; uint4* lA1 = (uint4*)&As[c1 * 8];
  uint4* lB0 = (uint4*)&Bs[c0 * 8]; uint4* lB1 = (uint4*)&Bs[c1 * 8];

  const int wm = (wave & 1) * 64, wn = (wave >> 1) * 64;
  const int rl = lane & 15, q = lane >> 4;

  f32x4 acc[4][4];
#pragma unroll
  for (int i = 0; i < 4; ++i)
#pragma unroll
    for (int j = 0; j < 4; ++j) acc[i][j] = (f32x4){0.f, 0.f, 0.f, 0.f};

  const bf16x8* AsV = (const bf16x8*)As;
  const bf16x8* BsV = (const bf16x8*)Bs;

  for (int k0 = 0; k0 < K; k0 += 32) {
    uint4 ra0 = *(const uint4*)(gA0 + k0);
    uint4 ra1 = *(const uint4*)(gA1 + k0);
    uint4 rb0 = *(const uint4*)(gB0 + k0);
    uint4 rb1 = *(const uint4*)(gB1 + k0);
    *lA0 = ra0; *lA1 = ra1; *lB0 = rb0; *lB1 = rb1;
    __syncthreads();
    bf16x8 af[4], bfv[4];
#pragma unroll
    for (int s = 0; s < 4; ++s) {
      af[s]  = AsV[(wm + s * 16 + rl) * 4 + q];
      bfv[s] = BsV[(wn + s * 16 + rl) * 4 + q];
    }
#pragma unroll
    for (int i = 0; i < 4; ++i)
#pragma unroll
      for (int j = 0; j < 4; ++j)
        acc[i][j] = __builtin_amdgcn_mfma_f32_16x16x32_bf16(af[i], bfv[j], acc[i][j], 0, 0, 0);
    __syncthreads();
  }

#pragma unroll
  for (int i = 0; i < 4; ++i) {
#pragma unroll
    for (int j = 0; j < 4; ++j) {
#pragma unroll
      for (int r = 0; r < 4; ++r) {
        int row = bm + wm + i * 16 + q * 4 + r;
        int col = bn + wn + j * 16 + rl;
        float v = acc[i][j][r];
        if (epi_l == 1) v = silu_f(v);
        if (epi == 2) ((float*)Cout)[(size_t)row * ldc + col] = v;
        else          ((u16*)Cout)[(size_t)row * ldc + col] = f2b(v);
      }
    }
  }
}

// ---------------------------------------------------------------------------
// Causal depthwise conv (K=4, fp32 weights) + SiLU, fwd + reversed.
// ---------------------------------------------------------------------------
__global__ void conv_kernel(
    const u16* __restrict__ xsg,
    const float* __restrict__ cw, const float* __restrict__ cb,
    const float* __restrict__ cwb, const float* __restrict__ cbb,
    u16* __restrict__ xc, u16* __restrict__ xcb)
{
  int idx = blockIdx.x * 256 + threadIdx.x;      // over ML*DI
  int d = idx % DI;
  int row = idx / DI;
  int l = row % LL, b = row / LL;
  const u16* base = xsg + (size_t)b * LL * 3072 + d;

  float4 wf = *(const float4*)(cw + d * 4);
  float4 wb = *(const float4*)(cwb + d * 4);
  float wfk[4] = {wf.x, wf.y, wf.z, wf.w};
  float wbk[4] = {wb.x, wb.y, wb.z, wb.w};

  float accf = cb[d];
  float accb = cbb[d];
#pragma unroll
  for (int k = 0; k < 4; ++k) {
    int ls = l - 3 + k;
    if (ls >= 0) {
      accf += wfk[k] * b2f(base[(size_t)ls * 3072]);
      accb += wbk[k] * b2f(base[(size_t)(LL - 1 - ls) * 3072]);
    }
  }
  xc[idx]  = f2b(silu_f(accf));
  xcb[idx] = f2b(silu_f(accb));
}

// ---------------------------------------------------------------------------
// delta = softplus(dt_low @ dtW^T + dtb), fp32 out.
// ---------------------------------------------------------------------------
__global__ __launch_bounds__(256) void delta_kernel(
    const float* __restrict__ proj_f, const float* __restrict__ proj_b,
    const float* __restrict__ dtW, const float* __restrict__ dtW_b,
    const float* __restrict__ dtb, const float* __restrict__ dtb_b,
    float* __restrict__ delta_f, float* __restrict__ delta_b)
{
  const int dir = blockIdx.z;
  const float* proj = dir ? proj_b : proj_f;
  const float* W = dir ? dtW_b : dtW;
  const float* bias = dir ? dtb_b : dtb;
  float* outp = dir ? delta_b : delta_f;
  const int row = blockIdx.x;
  const int d = blockIdx.y * 256 + threadIdx.x;

  __shared__ float dl[RNK];
  if (threadIdx.x < RNK) dl[threadIdx.x] = proj[(size_t)row * 128 + threadIdx.x];
  __syncthreads();

  float s = bias[d];
  const float4* w4 = (const float4*)(W + (size_t)d * RNK);
#pragma unroll
  for (int j = 0; j < RNK / 4; ++j) {
    float4 w = w4[j];
    s += dl[j * 4 + 0] * w.x + dl[j * 4 + 1] * w.y +
         dl[j * 4 + 2] * w.z + dl[j * 4 + 3] * w.w;
  }
  float sp = (s > 20.f) ? s : log1pf(__expf(s));
  outp[(size_t)row * DI + d] = sp;
}

// ---------------------------------------------------------------------------
// Segmented scan, phase A: per (dir,b,seg,d) compute Sdelta = sum(delta) and
// local end-state h_local[16] (h_in = 0). Channel-per-thread, B in LDS.
// ---------------------------------------------------------------------------
__global__ __launch_bounds__(256) void scan_sum(
    const float* __restrict__ df, const float* __restrict__ db,
    const u16* __restrict__ xcf, const u16* __restrict__ xcb,
    const float* __restrict__ pf, const float* __restrict__ pb,
    const float* __restrict__ A_log, const float* __restrict__ A_log_b,
    float* __restrict__ sdl, float* __restrict__ bs)
{
  const int dir = blockIdx.z / NSEG, seg = blockIdx.z % NSEG;
  const float* delta = dir ? db : df;
  const u16* xc = dir ? xcb : xcf;
  const float* proj = dir ? pb : pf;
  const float* Al = dir ? A_log_b : A_log;
  const int b = blockIdx.y;
  const int d = blockIdx.x * 256 + threadIdx.x;
  const int l0 = seg * SEGL;

  __shared__ float Bsh[SEGL][16];
  for (int i = threadIdx.x; i < SEGL * 16; i += 256) {
    int l = i >> 4, n = i & 15;
    Bsh[l][n] = proj[((size_t)b * LL + l0 + l) * 128 + 48 + n];
  }
  __syncthreads();

  float An[16];
#pragma unroll
  for (int n = 0; n < 16; ++n) An[n] = -__expf(Al[d * 16 + n]);

  float h[16];
#pragma unroll
  for (int n = 0; n < 16; ++n) h[n] = 0.f;
  float S = 0.f;

  const float* dbase = delta + ((size_t)b * LL + l0) * DI + d;
  const u16* xbase = xc + ((size_t)b * LL + l0) * DI + d;

  for (int g = 0; g < SEGL; g += 4) {
    float dl4[4], dx4[4];
#pragma unroll
    for (int j = 0; j < 4; ++j) {
      float dv = dbase[(size_t)(g + j) * DI];
      float xv = b2f(xbase[(size_t)(g + j) * DI]);
      dl4[j] = dv; dx4[j] = dv * xv;
    }
#pragma unroll
    for (int j = 0; j < 4; ++j) {
      S += dl4[j];
#pragma unroll
      for (int n = 0; n < 16; ++n)
        h[n] = __expf(dl4[j] * An[n]) * h[n] + dx4[j] * Bsh[g + j][n];
    }
  }

  size_t base = (((size_t)dir * BB + b) * NSEG + seg) * DI + d;
  sdl[base] = S;
#pragma unroll
  for (int n = 0; n < 16; ++n) bs[base * 16 + n] = h[n];
}

// ---------------------------------------------------------------------------
// Phase B: compose segment summaries into carry-ins. One thread per
// (dir,b,d,n). bs is read (summary) then overwritten (carry-in) per segment.
// ---------------------------------------------------------------------------
__global__ __launch_bounds__(256) void scan_carry(
    const float* __restrict__ A_log, const float* __restrict__ A_log_b,
    const float* __restrict__ sdl, float* __restrict__ bs)
{
  int idx = blockIdx.x * 256 + threadIdx.x;   // over 2*BB*DI*16
  int n = idx & 15;
  int t = idx >> 4;                           // dir*BB*DI + b*DI + d
  int d = t % DI;
  int b = (t / DI) % BB;
  int dir = t / (DI * BB);
  const float* Al = dir ? A_log_b : A_log;
  float An = -__expf(Al[d * 16 + n]);
  float h = 0.f;
  for (int s = 0; s < NSEG; ++s) {
    size_t base = (((size_t)dir * BB + b) * NSEG + s) * DI + d;
    float S = sdl[base];
    float bv = bs[base * 16 + n];
    bs[base * 16 + n] = h;                    // carry-in for segment s
    h = __expf(S * An) * h + bv;
  }
}

// ---------------------------------------------------------------------------
// Phase C: redo recurrence from carry-in, compute y (all 16 states in regs,
// B/C staged in LDS, coalesced y stores).
// ---------------------------------------------------------------------------
__global__ __launch_bounds__(256) void scan_apply(
    const float* __restrict__ df, const float* __restrict__ db,
    const u16* __restrict__ xcf, const u16* __restrict__ xcb,
    const float* __restrict__ pf, const float* __restrict__ pb,
    const float* __restrict__ A_log, const float* __restrict__ A_log_b,
    const float* __restrict__ Dp, const float* __restrict__ Dp_b,
    const float* __restrict__ bs,
    u16* __restrict__ y_f, u16* __restrict__ y_b)
{
  const int dir = blockIdx.z / NSEG, seg = blockIdx.z % NSEG;
  const float* delta = dir ? db : df;
  const u16* xc = dir ? xcb : xcf;
  const float* proj = dir ? pb : pf;
  const float* Al = dir ? A_log_b : A_log;
  const float* Dpp = dir ? Dp_b : Dp;
  u16* y = dir ? y_b : y_f;
  const int b = blockIdx.y;
  const int d = blockIdx.x * 256 + threadIdx.x;
  const int l0 = seg * SEGL;

  __shared__ float BCsh[SEGL][32];            // [l][0:16)=B, [16:32)=C
  for (int i = threadIdx.x; i < SEGL * 32; i += 256) {
    int l = i >> 5, j = i & 31;
    BCsh[l][j] = proj[((size_t)b * LL + l0 + l) * 128 + 48 + j];
  }
  __syncthreads();

  float An[16];
#pragma unroll
  for (int n = 0; n < 16; ++n) An[n] = -__expf(Al[d * 16 + n]);
  const float Dv = Dpp[d];

  float h[16];
  size_t cbase = (((size_t)dir * BB + b) * NSEG + seg) * DI + d;
#pragma unroll
  for (int n = 0; n < 16; ++n) h[n] = bs[cbase * 16 + n];

  const float* dbase = delta + ((size_t)b * LL + l0) * DI + d;
  const u16* xbase = xc + ((size_t)b * LL + l0) * DI + d;
  u16* ybase = y + ((size_t)b * LL + l0) * DI + d;

  for (int g = 0; g < SEGL; g += 4) {
    float dl4[4], xv4[4];
#pragma unroll
    for (int j = 0; j < 4; ++j) {
      dl4[j] = dbase[(size_t)(g + j) * DI];
      xv4[j] = b2f(xbase[(size_t)(g + j) * DI]);
    }
#pragma unroll
    for (int j = 0; j < 4; ++j) {
      float dx = dl4[j] * xv4[j];
      float yv = 0.f;
#pragma unroll
      for (int n = 0; n < 16; ++n) {
        h[n] = __expf(dl4[j] * An[n]) * h[n] + dx * BCsh[g + j][n];
        yv += h[n] * BCsh[g + j][16 + n];
      }
      ybase[(size_t)(g + j) * DI] = f2b(yv + Dv * xv4[j]);
    }
  }
}

// ---------------------------------------------------------------------------
// y_comb[l] = 0.5 * silu(z[l]) * (y_f[l] + y_b_rev[L-1-l]); in-place over yf.
// ---------------------------------------------------------------------------
__global__ void combine_kernel(
    const u16* __restrict__ ybr, const u16* __restrict__ xsg, u16* yf)
{
  int idx = blockIdx.x * 256 + threadIdx.x;      // over ML*DI
  int d = idx % DI;
  int row = idx / DI;
  int l = row % LL, b = row / LL;
  float g = b2f(xsg[(size_t)row * 3072 + DI + d]);
  float vb = b2f(ybr[((size_t)b * LL + (LL - 1 - l)) * DI + d]);
  float v = 0.5f * (b2f(yf[idx]) + vb) * g;
  yf[idx] = f2b(v);
}

// ---------------------------------------------------------------------------
extern "C" void kernel_launch(void* const* d_in, const int* in_sizes, int n_in,
                              void* d_out, int out_size, void* d_ws, size_t ws_size,
                              hipStream_t stream)
{
  const float* x       = (const float*)d_in[0];
  const float* Wis     = (const float*)d_in[1];
  const float* Wig     = (const float*)d_in[2];
  const float* conv_w  = (const float*)d_in[3];
  const float* conv_b  = (const float*)d_in[4];
  const float* conv_wb = (const float*)d_in[5];
  const float* conv_bb = (const float*)d_in[6];
  const float* W_dt    = (const float*)d_in[7];
  const float* W_B     = (const float*)d_in[8];
  const float* W_C     = (const float*)d_in[9];
  const float* dtW     = (const float*)d_in[10];
  const float* dtb     = (const float*)d_in[11];
  const float* A_log   = (const float*)d_in[12];
  const float* Dp      = (const float*)d_in[13];
  const float* W_dt_b  = (const float*)d_in[14];
  const float* W_B_b   = (const float*)d_in[15];
  const float* W_C_b   = (const float*)d_in[16];
  const float* dtW_b   = (const float*)d_in[17];
  const float* dtb_b   = (const float*)d_in[18];
  const float* A_log_b = (const float*)d_in[19];
  const float* Dp_b    = (const float*)d_in[20];
  const float* W_out   = (const float*)d_in[21];

  char* ws = (char*)d_ws;
  size_t off = 0;
  auto alloc = [&](size_t bytes) -> char* {
    char* p = ws + off; off += (bytes + 255) & ~(size_t)255; return p;
  };
  u16*   xb    = (u16*)alloc((size_t)ML * DM * 2);
  u16*   wisb  = (u16*)alloc((size_t)DI * DM * 2);
  u16*   wigb  = (u16*)alloc((size_t)DI * DM * 2);
  u16*   woutb = (u16*)alloc((size_t)DM * DI * 2);
  u16*   xsg = (u16*)alloc((size_t)ML * 3072 * 2);     // [xs | silu(z)]
  u16*   xc  = (u16*)alloc((size_t)ML * DI * 2);
  u16*   xcb = (u16*)alloc((size_t)ML * DI * 2);       // reversed space
  u16*   wcf = (u16*)alloc((size_t)128 * DI * 2);
  u16*   wcb = (u16*)alloc((size_t)128 * DI * 2);
  float* pf  = (float*)alloc((size_t)ML * 128 * 4);
  float* pb  = (float*)alloc((size_t)ML * 128 * 4);
  float* df  = (float*)alloc((size_t)ML * DI * 4);
  float* db  = (float*)alloc((size_t)ML * DI * 4);
  u16*   yf  = (u16*)alloc((size_t)ML * DI * 2);       // later holds combined y
  u16*   ybr = (u16*)alloc((size_t)ML * DI * 2);       // reversed space
  float* sdl = (float*)alloc((size_t)2 * BB * NSEG * DI * 4);          // 0.8 MB
  float* bs  = (float*)alloc((size_t)2 * BB * NSEG * DI * 16 * 4);     // 25 MB
  // total ~102 MB

  // 1. fp32->bf16 conversion + proj-weight concat
  const int conv_total = SEG_X + 3 * SEG_W + 2 * SEG_CAT;
  convert_kernel<<<(conv_total + 255) / 256, 256, 0, stream>>>(
      (const float4*)x, (const float4*)Wis, (const float4*)Wig, (const float4*)W_out,
      W_dt, W_B, W_C, W_dt_b, W_B_b, W_C_b,
      (u16x4_t*)xb, (u16x4_t*)wisb, (u16x4_t*)wigb, (u16x4_t*)woutb,
      (u16x4_t*)wcf, (u16x4_t*)wcb);

  // 2. in-proj: [xs | silu(z)] = x @ [Wis; Wig]^T
  gemm_bt<<<dim3(3072 / 128, ML / 128, 1), 256, 0, stream>>>(
      xb, wisb, wigb, DI, xsg, ML, 3072, DM, 3072, 0, nullptr, nullptr, nullptr);

  // 3. causal conv + silu (fwd + reversed)
  conv_kernel<<<(ML * DI) / 256, 256, 0, stream>>>(
      xsg, conv_w, conv_b, conv_wb, conv_bb, xc, xcb);

  // 4. proj GEMMs: [dt_low|Bm|Cm|pad] = xc @ wcat^T (fp32 out), both dirs
  gemm_bt<<<dim3(1, ML / 128, 2), 256, 0, stream>>>(
      xc, wcf, nullptr, 1 << 30, pf, ML, 128, DI, 128, 2, xcb, wcb, pb);

  // 5. delta (fp32, both dirs)
  delta_kernel<<<dim3(ML, DI / 256, 2), 256, 0, stream>>>(
      pf, pb, dtW, dtW_b, dtb, dtb_b, df, db);

  // 6. segmented scan: summaries -> carries -> apply
  scan_sum<<<dim3(DI / 256, BB, 2 * NSEG), 256, 0, stream>>>(
      df, db, xc, xcb, pf, pb, A_log, A_log_b, sdl, bs);
  scan_carry<<<(2 * BB * DI * 16) / 256, 256, 0, stream>>>(
      A_log, A_log_b, sdl, bs);
  scan_apply<<<dim3(DI / 256, BB, 2 * NSEG), 256, 0, stream>>>(
      df, db, xc, xcb, pf, pb, A_log, A_log_b, Dp, Dp_b, bs, yf, ybr);

  // 7. gated combine + un-reverse (in place over yf)
  combine_kernel<<<(ML * DI) / 256, 256, 0, stream>>>(ybr, xsg, yf);

  // 8. out-proj: out = yf @ W_out^T, FP32 to d_out
  gemm_bt<<<dim3(DM / 128, ML / 128, 1), 256, 0, stream>>>(
      yf, woutb, nullptr, 1 << 30, d_out, ML, DM, DI, DM, 2, nullptr, nullptr, nullptr);
}

// Round 8
// 338.262 us; speedup vs baseline: 1.9912x; 1.1168x over previous
//
#include <hip/hip_runtime.h>
#include <hip/hip_bf16.h>
#include <stdint.h>

// Problem dims (fixed by the reference)
#define DM 768
#define DI 1536
#define DSTATE 16
#define RNK 48
#define BB 2
#define LL 1024
#define ML (BB * LL)  // 2048 rows (b*l flattened)

// segmented scan config
#define NSEG 32
#define SEGL (LL / NSEG)   // 32

typedef unsigned short u16;
typedef __bf16 bf16x8 __attribute__((ext_vector_type(8)));
typedef float f32x4 __attribute__((ext_vector_type(4)));

struct __align__(8) u16x4_t { u16 x, y, z, w; };

__device__ __forceinline__ float b2f(u16 u) {
  union { uint32_t i; float f; } v; v.i = ((uint32_t)u) << 16; return v.f;
}
__device__ __forceinline__ u16 f2b(float f) {
  union { float f; uint32_t i; } v; v.f = f;
  uint32_t r = v.i + 0x7FFFu + ((v.i >> 16) & 1u);  // RNE
  return (u16)(r >> 16);
}
__device__ __forceinline__ float silu_f(float x) { return x / (1.f + __expf(-x)); }
__device__ __forceinline__ u16x4_t cvt4(float4 v) {
  u16x4_t o; o.x = f2b(v.x); o.y = f2b(v.y); o.z = f2b(v.z); o.w = f2b(v.w); return o;
}

// ---------------------------------------------------------------------------
// Fused fp32->bf16 conversion of all GEMM operands + proj-weight concat.
// ---------------------------------------------------------------------------
#define SEG_X    (ML * DM / 4)
#define SEG_W    (DI * DM / 4)
#define SEG_CAT  (128 * DI / 4)
__global__ __launch_bounds__(256) void convert_kernel(
    const float4* __restrict__ x, const float4* __restrict__ wis,
    const float4* __restrict__ wig, const float4* __restrict__ wout,
    const float* __restrict__ W_dt, const float* __restrict__ W_B,
    const float* __restrict__ W_C, const float* __restrict__ W_dt_b,
    const float* __restrict__ W_B_b, const float* __restrict__ W_C_b,
    u16x4_t* __restrict__ xb, u16x4_t* __restrict__ wisb,
    u16x4_t* __restrict__ wigb, u16x4_t* __restrict__ woutb,
    u16x4_t* __restrict__ wcf, u16x4_t* __restrict__ wcb)
{
  int idx = blockIdx.x * 256 + threadIdx.x;
  if (idx < SEG_X) { xb[idx] = cvt4(x[idx]); return; }
  idx -= SEG_X;
  if (idx < SEG_W) { wisb[idx] = cvt4(wis[idx]); return; }
  idx -= SEG_W;
  if (idx < SEG_W) { wigb[idx] = cvt4(wig[idx]); return; }
  idx -= SEG_W;
  if (idx < SEG_W) { woutb[idx] = cvt4(wout[idx]); return; }
  idx -= SEG_W;
  int dir = idx / SEG_CAT;
  int rem = idx % SEG_CAT;
  int row = rem / (DI / 4), k4 = rem % (DI / 4);
  const float* src = nullptr;
  if (row < 48)      src = (dir ? W_dt_b : W_dt) + (size_t)row * DI + k4 * 4;
  else if (row < 64) src = (dir ? W_B_b  : W_B)  + (size_t)(row - 48) * DI + k4 * 4;
  else if (row < 80) src = (dir ? W_C_b  : W_C)  + (size_t)(row - 64) * DI + k4 * 4;
  u16x4_t o;
  if (src) o = cvt4(*(const float4*)src);
  else { o.x = 0; o.y = 0; o.z = 0; o.w = 0; }
  (dir ? wcb : wcf)[rem] = o;
}

// ---------------------------------------------------------------------------
// Generic bf16 GEMM (validated rounds 3/4/6): C = A (MxK) @ B^T (NxK).
// 128x128 tile, 4 waves, 16x16x32 MFMA, uint4 staging.
// ---------------------------------------------------------------------------
__global__ __launch_bounds__(256) void gemm_bt(
    const u16* __restrict__ A, const u16* __restrict__ B0,
    const u16* __restrict__ B1, int Nsplit,
    void* __restrict__ Cout, int M, int N, int K, int ldc, int epi,
    const u16* __restrict__ A2, const u16* __restrict__ B2,
    void* __restrict__ C2)
{
  if (blockIdx.z) { A = A2; B0 = B2; Cout = C2; }
  __shared__ alignas(16) u16 As[128 * 32];
  __shared__ alignas(16) u16 Bs[128 * 32];
  const int tid = threadIdx.x;
  const int wave = tid >> 6, lane = tid & 63;
  const int bm = blockIdx.y * 128;
  const int bn = blockIdx.x * 128;

  const u16* Bmat = B0;
  int ncol0 = bn;
  int epi_l = epi;
  if (B1 != nullptr && bn >= Nsplit) { Bmat = B1; ncol0 = bn - Nsplit; epi_l = 1; }

  const int c0 = tid, c1 = tid + 256;
  const u16* gA0 = A + (size_t)(bm + (c0 >> 2)) * K + (c0 & 3) * 8;
  const u16* gA1 = A + (size_t)(bm + (c1 >> 2)) * K + (c1 & 3) * 8;
  const u16* gB0 = Bmat + (size_t)(ncol0 + (c0 >> 2)) * K + (c0 & 3) * 8;
  const u16* gB1 = Bmat + (size_t)(ncol0 + (c1 >> 2)) * K + (c1 & 3) * 8;
  uint4* lA0 = (uint4*)&As[c0 * 8]; uint4* lA1 = (uint4*)&As[c1 * 8];
  uint4* lB0 = (uint4*)&Bs[c0 * 8]; uint4* lB1 = (uint4*)&Bs[c1 * 8];

  const int wm = (wave & 1) * 64, wn = (wave >> 1) * 64;
  const int rl = lane & 15, q = lane >> 4;

  f32x4 acc[4][4];
#pragma unroll
  for (int i = 0; i < 4; ++i)
#pragma unroll
    for (int j = 0; j < 4; ++j) acc[i][j] = (f32x4){0.f, 0.f, 0.f, 0.f};

  const bf16x8* AsV = (const bf16x8*)As;
  const bf16x8* BsV = (const bf16x8*)Bs;

  for (int k0 = 0; k0 < K; k0 += 32) {
    uint4 ra0 = *(const uint4*)(gA0 + k0);
    uint4 ra1 = *(const uint4*)(gA1 + k0);
    uint4 rb0 = *(const uint4*)(gB0 + k0);
    uint4 rb1 = *(const uint4*)(gB1 + k0);
    *lA0 = ra0; *lA1 = ra1; *lB0 = rb0; *lB1 = rb1;
    __syncthreads();
    bf16x8 af[4], bfv[4];
#pragma unroll
    for (int s = 0; s < 4; ++s) {
      af[s]  = AsV[(wm + s * 16 + rl) * 4 + q];
      bfv[s] = BsV[(wn + s * 16 + rl) * 4 + q];
    }
#pragma unroll
    for (int i = 0; i < 4; ++i)
#pragma unroll
      for (int j = 0; j < 4; ++j)
        acc[i][j] = __builtin_amdgcn_mfma_f32_16x16x32_bf16(af[i], bfv[j], acc[i][j], 0, 0, 0);
    __syncthreads();
  }

#pragma unroll
  for (int i = 0; i < 4; ++i) {
#pragma unroll
    for (int j = 0; j < 4; ++j) {
#pragma unroll
      for (int r = 0; r < 4; ++r) {
        int row = bm + wm + i * 16 + q * 4 + r;
        int col = bn + wn + j * 16 + rl;
        float v = acc[i][j][r];
        if (epi_l == 1) v = silu_f(v);
        if (epi == 2) ((float*)Cout)[(size_t)row * ldc + col] = v;
        else          ((u16*)Cout)[(size_t)row * ldc + col] = f2b(v);
      }
    }
  }
}

// ---------------------------------------------------------------------------
// Causal depthwise conv (K=4, fp32 weights) + SiLU, fwd + reversed.
// ---------------------------------------------------------------------------
__global__ void conv_kernel(
    const u16* __restrict__ xsg,
    const float* __restrict__ cw, const float* __restrict__ cb,
    const float* __restrict__ cwb, const float* __restrict__ cbb,
    u16* __restrict__ xc, u16* __restrict__ xcb)
{
  int idx = blockIdx.x * 256 + threadIdx.x;      // over ML*DI
  int d = idx % DI;
  int row = idx / DI;
  int l = row % LL, b = row / LL;
  const u16* base = xsg + (size_t)b * LL * 3072 + d;

  float4 wf = *(const float4*)(cw + d * 4);
  float4 wb = *(const float4*)(cwb + d * 4);
  float wfk[4] = {wf.x, wf.y, wf.z, wf.w};
  float wbk[4] = {wb.x, wb.y, wb.z, wb.w};

  float accf = cb[d];
  float accb = cbb[d];
#pragma unroll
  for (int k = 0; k < 4; ++k) {
    int ls = l - 3 + k;
    if (ls >= 0) {
      accf += wfk[k] * b2f(base[(size_t)ls * 3072]);
      accb += wbk[k] * b2f(base[(size_t)(LL - 1 - ls) * 3072]);
    }
  }
  xc[idx]  = f2b(silu_f(accf));
  xcb[idx] = f2b(silu_f(accb));
}

// ---------------------------------------------------------------------------
// delta = softplus(dt_low @ dtW^T + dtb), fp32 out.
// ROUND-7 REWORK: 16 rows per block; dtW row lives in 48 VGPRs (loaded once,
// was re-fetched from L2 per row => 1.2 GB L2 traffic); dt_low rows in LDS
// (float4 broadcast reads). Same per-element math/order => bit-identical.
// ---------------------------------------------------------------------------
#define DROWS 16
__global__ __launch_bounds__(256) void delta_kernel(
    const float* __restrict__ proj_f, const float* __restrict__ proj_b,
    const float* __restrict__ dtW, const float* __restrict__ dtW_b,
    const float* __restrict__ dtb, const float* __restrict__ dtb_b,
    float* __restrict__ delta_f, float* __restrict__ delta_b)
{
  const int dir = blockIdx.z;
  const float* proj = dir ? proj_b : proj_f;
  const float* W = dir ? dtW_b : dtW;
  const float* bias = dir ? dtb_b : dtb;
  float* outp = dir ? delta_b : delta_f;
  const int r0 = blockIdx.x * DROWS;                 // rows [r0, r0+16)
  const int d = blockIdx.y * 256 + threadIdx.x;      // 0..1535

  __shared__ float dl[DROWS][RNK];                   // 3 KB
  for (int i = threadIdx.x; i < DROWS * RNK; i += 256) {
    int r = i / RNK, j = i % RNK;
    dl[r][j] = proj[(size_t)(r0 + r) * 128 + j];
  }
  __syncthreads();

  float w[RNK];
  const float4* w4 = (const float4*)(W + (size_t)d * RNK);
#pragma unroll
  for (int j = 0; j < RNK / 4; ++j) {
    float4 t = w4[j];
    w[4 * j] = t.x; w[4 * j + 1] = t.y; w[4 * j + 2] = t.z; w[4 * j + 3] = t.w;
  }
  const float bv = bias[d];

#pragma unroll
  for (int r = 0; r < DROWS; ++r) {
    float s = bv;
#pragma unroll
    for (int j4 = 0; j4 < RNK / 4; ++j4) {
      float4 dv = *(const float4*)&dl[r][j4 * 4];    // LDS b128 broadcast
      s += dv.x * w[4 * j4] + dv.y * w[4 * j4 + 1] +
           dv.z * w[4 * j4 + 2] + dv.w * w[4 * j4 + 3];
    }
    float sp = (s > 20.f) ? s : log1pf(__expf(s));
    outp[(size_t)(r0 + r) * DI + d] = sp;
  }
}

// ---------------------------------------------------------------------------
// Segmented scan, phase A: per (dir,b,seg,d) compute Sdelta = sum(delta) and
// local end-state h_local[16] (h_in = 0). Channel-per-thread, B in LDS.
// ---------------------------------------------------------------------------
__global__ __launch_bounds__(256) void scan_sum(
    const float* __restrict__ df, const float* __restrict__ db,
    const u16* __restrict__ xcf, const u16* __restrict__ xcb,
    const float* __restrict__ pf, const float* __restrict__ pb,
    const float* __restrict__ A_log, const float* __restrict__ A_log_b,
    float* __restrict__ sdl, float* __restrict__ bs)
{
  const int dir = blockIdx.z / NSEG, seg = blockIdx.z % NSEG;
  const float* delta = dir ? db : df;
  const u16* xc = dir ? xcb : xcf;
  const float* proj = dir ? pb : pf;
  const float* Al = dir ? A_log_b : A_log;
  const int b = blockIdx.y;
  const int d = blockIdx.x * 256 + threadIdx.x;
  const int l0 = seg * SEGL;

  __shared__ float Bsh[SEGL][16];
  for (int i = threadIdx.x; i < SEGL * 16; i += 256) {
    int l = i >> 4, n = i & 15;
    Bsh[l][n] = proj[((size_t)b * LL + l0 + l) * 128 + 48 + n];
  }
  __syncthreads();

  float An[16];
#pragma unroll
  for (int n = 0; n < 16; ++n) An[n] = -__expf(Al[d * 16 + n]);

  float h[16];
#pragma unroll
  for (int n = 0; n < 16; ++n) h[n] = 0.f;
  float S = 0.f;

  const float* dbase = delta + ((size_t)b * LL + l0) * DI + d;
  const u16* xbase = xc + ((size_t)b * LL + l0) * DI + d;

  for (int g = 0; g < SEGL; g += 4) {
    float dl4[4], dx4[4];
#pragma unroll
    for (int j = 0; j < 4; ++j) {
      float dv = dbase[(size_t)(g + j) * DI];
      float xv = b2f(xbase[(size_t)(g + j) * DI]);
      dl4[j] = dv; dx4[j] = dv * xv;
    }
#pragma unroll
    for (int j = 0; j < 4; ++j) {
      S += dl4[j];
#pragma unroll
      for (int n = 0; n < 16; ++n)
        h[n] = __expf(dl4[j] * An[n]) * h[n] + dx4[j] * Bsh[g + j][n];
    }
  }

  size_t base = (((size_t)dir * BB + b) * NSEG + seg) * DI + d;
  sdl[base] = S;
#pragma unroll
  for (int n = 0; n < 16; ++n) bs[base * 16 + n] = h[n];
}

// ---------------------------------------------------------------------------
// Phase B: compose segment summaries into carry-ins. One thread per
// (dir,b,d,n). bs is read (summary) then overwritten (carry-in) per segment.
// ---------------------------------------------------------------------------
__global__ __launch_bounds__(256) void scan_carry(
    const float* __restrict__ A_log, const float* __restrict__ A_log_b,
    const float* __restrict__ sdl, float* __restrict__ bs)
{
  int idx = blockIdx.x * 256 + threadIdx.x;   // over 2*BB*DI*16
  int n = idx & 15;
  int t = idx >> 4;                           // dir*BB*DI + b*DI + d
  int d = t % DI;
  int b = (t / DI) % BB;
  int dir = t / (DI * BB);
  const float* Al = dir ? A_log_b : A_log;
  float An = -__expf(Al[d * 16 + n]);
  float h = 0.f;
  for (int s = 0; s < NSEG; ++s) {
    size_t base = (((size_t)dir * BB + b) * NSEG + s) * DI + d;
    float S = sdl[base];
    float bv = bs[base * 16 + n];
    bs[base * 16 + n] = h;                    // carry-in for segment s
    h = __expf(S * An) * h + bv;
  }
}

// ---------------------------------------------------------------------------
// Phase C: redo recurrence from carry-in, compute y (all 16 states in regs,
// B/C staged in LDS, coalesced y stores).
// ---------------------------------------------------------------------------
__global__ __launch_bounds__(256) void scan_apply(
    const float* __restrict__ df, const float* __restrict__ db,
    const u16* __restrict__ xcf, const u16* __restrict__ xcb,
    const float* __restrict__ pf, const float* __restrict__ pb,
    const float* __restrict__ A_log, const float* __restrict__ A_log_b,
    const float* __restrict__ Dp, const float* __restrict__ Dp_b,
    const float* __restrict__ bs,
    u16* __restrict__ y_f, u16* __restrict__ y_b)
{
  const int dir = blockIdx.z / NSEG, seg = blockIdx.z % NSEG;
  const float* delta = dir ? db : df;
  const u16* xc = dir ? xcb : xcf;
  const float* proj = dir ? pb : pf;
  const float* Al = dir ? A_log_b : A_log;
  const float* Dpp = dir ? Dp_b : Dp;
  u16* y = dir ? y_b : y_f;
  const int b = blockIdx.y;
  const int d = blockIdx.x * 256 + threadIdx.x;
  const int l0 = seg * SEGL;

  __shared__ float BCsh[SEGL][32];            // [l][0:16)=B, [16:32)=C
  for (int i = threadIdx.x; i < SEGL * 32; i += 256) {
    int l = i >> 5, j = i & 31;
    BCsh[l][j] = proj[((size_t)b * LL + l0 + l) * 128 + 48 + j];
  }
  __syncthreads();

  float An[16];
#pragma unroll
  for (int n = 0; n < 16; ++n) An[n] = -__expf(Al[d * 16 + n]);
  const float Dv = Dpp[d];

  float h[16];
  size_t cbase = (((size_t)dir * BB + b) * NSEG + seg) * DI + d;
#pragma unroll
  for (int n = 0; n < 16; ++n) h[n] = bs[cbase * 16 + n];

  const float* dbase = delta + ((size_t)b * LL + l0) * DI + d;
  const u16* xbase = xc + ((size_t)b * LL + l0) * DI + d;
  u16* ybase = y + ((size_t)b * LL + l0) * DI + d;

  for (int g = 0; g < SEGL; g += 4) {
    float dl4[4], xv4[4];
#pragma unroll
    for (int j = 0; j < 4; ++j) {
      dl4[j] = dbase[(size_t)(g + j) * DI];
      xv4[j] = b2f(xbase[(size_t)(g + j) * DI]);
    }
#pragma unroll
    for (int j = 0; j < 4; ++j) {
      float dx = dl4[j] * xv4[j];
      float yv = 0.f;
#pragma unroll
      for (int n = 0; n < 16; ++n) {
        h[n] = __expf(dl4[j] * An[n]) * h[n] + dx * BCsh[g + j][n];
        yv += h[n] * BCsh[g + j][16 + n];
      }
      ybase[(size_t)(g + j) * DI] = f2b(yv + Dv * xv4[j]);
    }
  }
}

// ---------------------------------------------------------------------------
// y_comb[l] = 0.5 * silu(z[l]) * (y_f[l] + y_b_rev[L-1-l]); in-place over yf.
// ---------------------------------------------------------------------------
__global__ void combine_kernel(
    const u16* __restrict__ ybr, const u16* __restrict__ xsg, u16* yf)
{
  int idx = blockIdx.x * 256 + threadIdx.x;      // over ML*DI
  int d = idx % DI;
  int row = idx / DI;
  int l = row % LL, b = row / LL;
  float g = b2f(xsg[(size_t)row * 3072 + DI + d]);
  float vb = b2f(ybr[((size_t)b * LL + (LL - 1 - l)) * DI + d]);
  float v = 0.5f * (b2f(yf[idx]) + vb) * g;
  yf[idx] = f2b(v);
}

// ---------------------------------------------------------------------------
extern "C" void kernel_launch(void* const* d_in, const int* in_sizes, int n_in,
                              void* d_out, int out_size, void* d_ws, size_t ws_size,
                              hipStream_t stream)
{
  const float* x       = (const float*)d_in[0];
  const float* Wis     = (const float*)d_in[1];
  const float* Wig     = (const float*)d_in[2];
  const float* conv_w  = (const float*)d_in[3];
  const float* conv_b  = (const float*)d_in[4];
  const float* conv_wb = (const float*)d_in[5];
  const float* conv_bb = (const float*)d_in[6];
  const float* W_dt    = (const float*)d_in[7];
  const float* W_B     = (const float*)d_in[8];
  const float* W_C     = (const float*)d_in[9];
  const float* dtW     = (const float*)d_in[10];
  const float* dtb     = (const float*)d_in[11];
  const float* A_log   = (const float*)d_in[12];
  const float* Dp      = (const float*)d_in[13];
  const float* W_dt_b  = (const float*)d_in[14];
  const float* W_B_b   = (const float*)d_in[15];
  const float* W_C_b   = (const float*)d_in[16];
  const float* dtW_b   = (const float*)d_in[17];
  const float* dtb_b   = (const float*)d_in[18];
  const float* A_log_b = (const float*)d_in[19];
  const float* Dp_b    = (const float*)d_in[20];
  const float* W_out   = (const float*)d_in[21];

  char* ws = (char*)d_ws;
  size_t off = 0;
  auto alloc = [&](size_t bytes) -> char* {
    char* p = ws + off; off += (bytes + 255) & ~(size_t)255; return p;
  };
  u16*   xb    = (u16*)alloc((size_t)ML * DM * 2);
  u16*   wisb  = (u16*)alloc((size_t)DI * DM * 2);
  u16*   wigb  = (u16*)alloc((size_t)DI * DM * 2);
  u16*   woutb = (u16*)alloc((size_t)DM * DI * 2);
  u16*   xsg = (u16*)alloc((size_t)ML * 3072 * 2);     // [xs | silu(z)]
  u16*   xc  = (u16*)alloc((size_t)ML * DI * 2);
  u16*   xcb = (u16*)alloc((size_t)ML * DI * 2);       // reversed space
  u16*   wcf = (u16*)alloc((size_t)128 * DI * 2);
  u16*   wcb = (u16*)alloc((size_t)128 * DI * 2);
  float* pf  = (float*)alloc((size_t)ML * 128 * 4);
  float* pb  = (float*)alloc((size_t)ML * 128 * 4);
  float* df  = (float*)alloc((size_t)ML * DI * 4);
  float* db  = (float*)alloc((size_t)ML * DI * 4);
  u16*   yf  = (u16*)alloc((size_t)ML * DI * 2);       // later holds combined y
  u16*   ybr = (u16*)alloc((size_t)ML * DI * 2);       // reversed space
  float* sdl = (float*)alloc((size_t)2 * BB * NSEG * DI * 4);          // 0.8 MB
  float* bs  = (float*)alloc((size_t)2 * BB * NSEG * DI * 16 * 4);     // 25 MB
  // total ~102 MB

  // 1. fp32->bf16 conversion + proj-weight concat
  const int conv_total = SEG_X + 3 * SEG_W + 2 * SEG_CAT;
  convert_kernel<<<(conv_total + 255) / 256, 256, 0, stream>>>(
      (const float4*)x, (const float4*)Wis, (const float4*)Wig, (const float4*)W_out,
      W_dt, W_B, W_C, W_dt_b, W_B_b, W_C_b,
      (u16x4_t*)xb, (u16x4_t*)wisb, (u16x4_t*)wigb, (u16x4_t*)woutb,
      (u16x4_t*)wcf, (u16x4_t*)wcb);

  // 2. in-proj: [xs | silu(z)] = x @ [Wis; Wig]^T
  gemm_bt<<<dim3(3072 / 128, ML / 128, 1), 256, 0, stream>>>(
      xb, wisb, wigb, DI, xsg, ML, 3072, DM, 3072, 0, nullptr, nullptr, nullptr);

  // 3. causal conv + silu (fwd + reversed)
  conv_kernel<<<(ML * DI) / 256, 256, 0, stream>>>(
      xsg, conv_w, conv_b, conv_wb, conv_bb, xc, xcb);

  // 4. proj GEMMs: [dt_low|Bm|Cm|pad] = xc @ wcat^T (fp32 out), both dirs
  gemm_bt<<<dim3(1, ML / 128, 2), 256, 0, stream>>>(
      xc, wcf, nullptr, 1 << 30, pf, ML, 128, DI, 128, 2, xcb, wcb, pb);

  // 5. delta (fp32, both dirs) — row-tiled rework
  delta_kernel<<<dim3(ML / DROWS, DI / 256, 2), 256, 0, stream>>>(
      pf, pb, dtW, dtW_b, dtb, dtb_b, df, db);

  // 6. segmented scan: summaries -> carries -> apply
  scan_sum<<<dim3(DI / 256, BB, 2 * NSEG), 256, 0, stream>>>(
      df, db, xc, xcb, pf, pb, A_log, A_log_b, sdl, bs);
  scan_carry<<<(2 * BB * DI * 16) / 256, 256, 0, stream>>>(
      A_log, A_log_b, sdl, bs);
  scan_apply<<<dim3(DI / 256, BB, 2 * NSEG), 256, 0, stream>>>(
      df, db, xc, xcb, pf, pb, A_log, A_log_b, Dp, Dp_b, bs, yf, ybr);

  // 7. gated combine + un-reverse (in place over yf)
  combine_kernel<<<(ML * DI) / 256, 256, 0, stream>>>(ybr, xsg, yf);

  // 8. out-proj: out = yf @ W_out^T, FP32 to d_out
  gemm_bt<<<dim3(DM / 128, ML / 128, 1), 256, 0, stream>>>(
      yf, woutb, nullptr, 1 << 30, d_out, ML, DM, DI, DM, 2, nullptr, nullptr, nullptr);
}